// Round 11
// baseline (17.122 us; speedup 1.0000x reference)
//
#include <hip/hip_runtime.h>
#include <math.h>

// ---------------- constants (atomic units) ----------------
constexpr double B2A   = 0.52917721067;
constexpr double H2KJ  = 2625.499638;
constexpr float  RCUT2F = (float)((10.0 / B2A) * (10.0 / B2A));

constexpr double Zc_[2]   = {3.61565, 0.93619};
constexpr double MONO_[2] = {-0.390896, 0.195448};
constexpr double QSH_[2]  = {MONO_[0] - Zc_[0], MONO_[1] - Zc_[1]};
constexpr double DIPO_[2][3] = {{0.0, 0.0, -0.094298},
                                {0.0910288, 0.0, -0.207851}};
constexpr double QS_[2][5] = {{-0.330685, 0.0, 0.0, 0.869923, 0.0},
                              {-0.0739388, 0.0929482, 0.0, 0.00532425, 0.0}};
constexpr double B_EL_[2]  = {2.13358, 2.33322};
constexpr double B_PA_[2]  = {2.1975, 1.96474};
constexpr double SPA_[2]   = {6.50923, 0.527804};
constexpr double KD_PA_[2] = {-5.61925, -0.515584};
constexpr double KQ_PA_[2] = {-1.56567, -0.440164};
constexpr double C6_[2]    = {35.8289, 1.98954};
constexpr double B_D_[2]   = {1.84302, 1.30993};
constexpr double AD_[2][3] = {{4.45992, 6.07259, 4.55391},
                              {2.22001, 1.66835, 0.183855}};
constexpr double ETA_[2]   = {6.18699e-06 * 2.0, 0.561535 * 2.0};
constexpr double B_XP_[2]  = {2.73582, 2.04028};
constexpr double SXP_[2]   = {1.26592, 0.200089};
constexpr double B_CT_[2]  = {1.89485, 2.36763};
constexpr double SACC_[2]  = {-0.67857, 1.36735};
constexpr double SDON_[2]  = {0.757752, 0.00888982};
constexpr double KD_DO_[2] = {-0.512036, -0.0511668};
constexpr double KQ_DO_[2] = {-0.208186, 0.0568152};
constexpr double EPS_OFF = 0.380979;

constexpr double D_M   = 524.265 / H2KJ;
constexpr double K_B   = 5098.15 / H2KJ * B2A * B2A;
constexpr double B_EQ  = 0.958413 / B2A;
constexpr double K_BB  = -61.1423 / H2KJ * B2A * B2A;
constexpr double K_BA  = -159.886 / H2KJ * B2A;
constexpr double TH_EQ = 104.4234 * M_PI / 180.0;
constexpr double K_TH  = 452.183 / H2KJ;
constexpr double SQ32  = 0.86602540378443864676;

// local-frame quadrupole (traceless Cartesian), /3 folded; q21s=q22s=0 -> only xx,yy,zz,xz
constexpr double QLXX_[2] = {(-0.5 * QS_[0][0] + SQ32 * QS_[0][3]) / 3.0,
                             (-0.5 * QS_[1][0] + SQ32 * QS_[1][3]) / 3.0};
constexpr double QLYY_[2] = {(-0.5 * QS_[0][0] - SQ32 * QS_[0][3]) / 3.0,
                             (-0.5 * QS_[1][0] - SQ32 * QS_[1][3]) / 3.0};
constexpr double QLZZ_[2] = {QS_[0][0] / 3.0, QS_[1][0] / 3.0};
constexpr double QLXZ_[2] = {SQ32 * QS_[0][1] / 3.0, SQ32 * QS_[1][1] / 3.0};
constexpr double DIP0_[2] = {DIPO_[0][0], DIPO_[1][0]};
constexpr double DIP2_[2] = {DIPO_[0][2], DIPO_[1][2]};

#define MAXN 768
#define NWAVE 4
#define TF(A, t) ((t) ? (float)A[1] : (float)A[0])
#define S(x) (tb ? x##1 : x##0)

// ---------------- f32 vec helpers ----------------
struct f3 { float x, y, z; };
__device__ inline f3 operator-(f3 a, f3 b) { return {a.x - b.x, a.y - b.y, a.z - b.z}; }
__device__ inline f3 operator+(f3 a, f3 b) { return {a.x + b.x, a.y + b.y, a.z + b.z}; }
__device__ inline f3 operator*(f3 a, float s) { return {a.x * s, a.y * s, a.z * s}; }
__device__ inline float dotf(f3 a, f3 b) { return a.x * b.x + a.y * b.y + a.z * b.z; }
__device__ inline f3 crossf(f3 a, f3 b) {
    return {a.y * b.z - a.z * b.y, a.z * b.x - a.x * b.z, a.x * b.y - a.y * b.x};
}
__device__ inline f3 normf(f3 a) { float s = rsqrtf(dotf(a, a)); return a * s; }
__device__ inline f3 getcf(const float* c, int i) {
    return {c[3 * i], c[3 * i + 1], c[3 * i + 2]};
}

// box context: general 3x3 + fast diagonal path (uniform runtime select)
struct BoxF {
    float bx[3][3], bi[3][3];
    float Lx, Ly, Lz, iLx, iLy, iLz;
    bool diag;
};
__device__ inline void load_boxctx(const float* box, BoxF& B) {
    for (int i = 0; i < 3; ++i)
        for (int j = 0; j < 3; ++j) B.bx[i][j] = box[i * 3 + j];
    B.diag = (box[1] == 0.f && box[2] == 0.f && box[3] == 0.f &&
              box[5] == 0.f && box[6] == 0.f && box[7] == 0.f);
    float a = B.bx[0][0], b = B.bx[0][1], c = B.bx[0][2];
    float d = B.bx[1][0], e = B.bx[1][1], f = B.bx[1][2];
    float g = B.bx[2][0], h = B.bx[2][1], i2 = B.bx[2][2];
    float A =  (e * i2 - f * h), Bb = -(d * i2 - f * g), C =  (d * h - e * g);
    float D = -(b * i2 - c * h), E =  (a * i2 - c * g), F = -(a * h - b * g);
    float G =  (b * f - c * e),  H = -(a * f - c * d),  I =  (a * e - b * d);
    float s = 1.0f / (a * A + b * Bb + c * C);
    B.bi[0][0] = A * s;  B.bi[0][1] = D * s; B.bi[0][2] = G * s;
    B.bi[1][0] = Bb * s; B.bi[1][1] = E * s; B.bi[1][2] = H * s;
    B.bi[2][0] = C * s;  B.bi[2][1] = F * s; B.bi[2][2] = I * s;
    B.Lx = B.bx[0][0]; B.Ly = B.bx[1][1]; B.Lz = B.bx[2][2];
    B.iLx = 1.f / B.Lx; B.iLy = 1.f / B.Ly; B.iLz = 1.f / B.Lz;
}
__device__ inline f3 pbcf(f3 d, const BoxF& B) {
    if (B.diag) {   // uniform branch
        d.x -= rintf(d.x * B.iLx) * B.Lx;
        d.y -= rintf(d.y * B.iLy) * B.Ly;
        d.z -= rintf(d.z * B.iLz) * B.Lz;
        return d;
    }
    float s0 = rintf(d.x * B.bi[0][0] + d.y * B.bi[1][0] + d.z * B.bi[2][0]);
    float s1 = rintf(d.x * B.bi[0][1] + d.y * B.bi[1][1] + d.z * B.bi[2][1]);
    float s2 = rintf(d.x * B.bi[0][2] + d.y * B.bi[1][2] + d.z * B.bi[2][2]);
    d.x -= s0 * B.bx[0][0] + s1 * B.bx[1][0] + s2 * B.bx[2][0];
    d.y -= s0 * B.bx[0][1] + s1 * B.bx[1][1] + s2 * B.bx[2][1];
    d.z -= s0 * B.bx[0][2] + s1 * B.bx[1][2] + s2 * B.bx[2][2];
    return d;
}
__device__ inline float f1mf(float u) { return -__expf(-u) * (1.0f + 0.5f * u); }  // f1 - 1

// ---------------- frame (local axes) ----------------
__device__ inline void calc_frame(const float* coords, const BoxF& B,
                                  int n, float R[3][3], int* tt) {
    int w = n / 3, m = n - w * 3, o = w * 3;
    int zat = (m == 0) ? n + 1 : o;
    int xat = (m == 0) ? n + 2 : ((m == 1) ? n + 1 : n - 1);
    f3 cn = getcf(coords, n);
    f3 uz = normf(pbcf(getcf(coords, zat) - cn, B));
    f3 ux = normf(pbcf(getcf(coords, xat) - cn, B));
    f3 zax = (m == 0) ? normf(uz + ux) : uz;
    f3 xax = normf(ux - zax * dotf(ux, zax));
    f3 yax = crossf(zax, xax);
    R[0][0] = xax.x; R[0][1] = yax.x; R[0][2] = zax.x;
    R[1][0] = xax.y; R[1][1] = yax.y; R[1][2] = zax.y;
    R[2][0] = xax.z; R[2][1] = yax.z; R[2][2] = zax.z;
    *tt = (m == 0) ? 0 : 1;
}

// rotated multipoles: M = [mu0,mu1,mu2, Qxx,Qxy,Qxz,Qyy,Qyz,Qzz]
__device__ inline void rot_muQ(const float R[3][3], int t, float M[9]) {
    float d0 = TF(DIP0_, t), d2 = TF(DIP2_, t);
    M[0] = R[0][0] * d0 + R[0][2] * d2;
    M[1] = R[1][0] * d0 + R[1][2] * d2;
    M[2] = R[2][0] * d0 + R[2][2] * d2;
    float qlxx = TF(QLXX_, t), qlyy = TF(QLYY_, t), qlzz = TF(QLZZ_, t), qlxz = TF(QLXZ_, t);
    float Bq[3][3];
    for (int p = 0; p < 3; ++p) {
        Bq[p][0] = R[p][0] * qlxx + R[p][2] * qlxz;
        Bq[p][1] = R[p][1] * qlyy;
        Bq[p][2] = R[p][0] * qlxz + R[p][2] * qlzz;
    }
    M[3] = Bq[0][0] * R[0][0] + Bq[0][1] * R[0][1] + Bq[0][2] * R[0][2];
    M[4] = Bq[0][0] * R[1][0] + Bq[0][1] * R[1][1] + Bq[0][2] * R[1][2];
    M[5] = Bq[0][0] * R[2][0] + Bq[0][1] * R[2][1] + Bq[0][2] * R[2][2];
    M[6] = Bq[1][0] * R[1][0] + Bq[1][1] * R[1][1] + Bq[1][2] * R[1][2];
    M[7] = Bq[1][0] * R[2][0] + Bq[1][1] * R[2][1] + Bq[1][2] * R[2][2];
    M[8] = Bq[2][0] * R[2][0] + Bq[2][1] * R[2][1] + Bq[2][2] * R[2][2];
}

__device__ inline float wredf(float v) {
    for (int off = 32; off > 0; off >>= 1) v += __shfl_xor(v, off);
    return v;
}
__device__ inline double wredd(double v) {
    for (int off = 32; off > 0; off >>= 1) v += __shfl_xor(v, off);
    return v;
}

// =============== kernel 1: block(256, 4 waves) per atom, block-balanced ===========
__global__ void __launch_bounds__(256, 3)
k_main(const float* __restrict__ coords, const float* __restrict__ box,
       double* __restrict__ wsd, int N) {
    __shared__ float4 sh_list[MAXN];      // per-wave compacted (dr, b) segments
    __shared__ float  sh_muQ[MAXN * 9];   // multipoles of survivors, slot-parallel
    __shared__ double sh_red[NWAVE * 5];
    __shared__ int    sh_cnt[NWAVE];

    int a = blockIdx.x;
    int tid = threadIdx.x;
    int w = tid >> 6, lane = tid & 63;
    BoxF B;
    load_boxctx(box, B);

    int wa = a / 3;
    int ta = (a - wa * 3) ? 1 : 0;
    f3 ca = getcf(coords, a);

    // own-atom frame + multipoles (uniform across block)
    float Ra[3][3]; int tt0;
    calc_frame(coords, B, a, Ra, &tt0);
    float MA[9];
    rot_muQ(Ra, ta, MA);
    f3 mua = {MA[0], MA[1], MA[2]};
    float Qaxx = MA[3], Qaxy = MA[4], Qaxz = MA[5], Qayy = MA[6], Qayz = MA[7], Qazz = MA[8];

    // ---- phase 1: per-wave cutoff compaction into own LDS segment ----
    int chunks = (N + 64 * NWAVE - 1) / (64 * NWAVE);
    int seg = chunks * 64;
    int base = w * seg;
    int cnt = 0;
    for (int k = 0; k < chunks; ++k) {
        int b = base + k * 64 + lane;
        bool pred = false;
        f3 dr = {0.f, 0.f, 0.f};
        if (b < N) {
            int wb = b / 3;
            dr = pbcf(getcf(coords, b) - ca, B);
            pred = (wb != wa) && (dotf(dr, dr) < RCUT2F);
        }
        unsigned long long mask = __ballot(pred);
        int pref = __popcll(mask & ((1ull << lane) - 1ull));
        if (pred) sh_list[base + cnt + pref] = make_float4(dr.x, dr.y, dr.z, __int_as_float(b));
        cnt += __popcll(mask);
    }
    if (lane == 0) sh_cnt[w] = cnt;
    __syncthreads();

    // prefix map over the 4 gappy segments (block-balanced work distribution)
    int c0 = sh_cnt[0], c1 = sh_cnt[1], c2 = sh_cnt[2], c3 = sh_cnt[3];
    int p1 = c0, p2 = p1 + c1, p3 = p2 + c2;
    int total = p3 + c3;
#define MAP_SLOT(g, slot)                                                  \
    int slot;                                                              \
    {                                                                      \
        int s_, off_;                                                      \
        if ((g) < p1)      { s_ = 0; off_ = (g); }                         \
        else if ((g) < p2) { s_ = 1; off_ = (g) - p1; }                    \
        else if ((g) < p3) { s_ = 2; off_ = (g) - p2; }                    \
        else               { s_ = 3; off_ = (g) - p3; }                    \
        slot = s_ * seg + off_;                                            \
    }

    // ---- phase 1b: multipoles for SURVIVORS only (block-strided) ----
    for (int g = tid; g < total; g += 256) {
        MAP_SLOT(g, slot);
        int b = __float_as_int(sh_list[slot].w);
        float Rb[3][3]; int tb;
        calc_frame(coords, B, b, Rb, &tb);
        float MB[9];
        rot_muQ(Rb, tb, MB);
        float* dst = &sh_muQ[slot * 9];
        for (int k = 0; k < 9; ++k) dst[k] = MB[k];
    }
    __syncthreads();

    // ---- type-pair dual constants ----
    float Zi = TF(Zc_, ta), qi = TF(QSH_, ta), qti = Zi + qi;
    float beli = TF(B_EL_, ta);
    float belj0 = (float)B_EL_[0], belj1 = (float)B_EL_[1];
    float bije0 = sqrtf(beli * belj0), bije1 = sqrtf(beli * belj1);
    float qtj0 = (float)(Zc_[0] + QSH_[0]), qtj1 = (float)(Zc_[1] + QSH_[1]);
    float Ziqj0 = Zi * (float)QSH_[0], Ziqj1 = Zi * (float)QSH_[1];
    float Zjqi0 = (float)Zc_[0] * qi, Zjqi1 = (float)Zc_[1] * qi;
    float qiqj0 = qi * (float)QSH_[0], qiqj1 = qi * (float)QSH_[1];
    float qq0 = qti * qtj0, qq1 = qti * qtj1;
    float sacci = TF(SACC_, ta);
    float saccj0 = (float)SACC_[0], saccj1 = (float)SACC_[1];
    float sdi = TF(SDON_, ta), kddi = TF(KD_DO_, ta), kqdi = TF(KQ_DO_, ta);
    float sdj0 = (float)SDON_[0], sdj1 = (float)SDON_[1];
    float kddj0 = (float)KD_DO_[0], kddj1 = (float)KD_DO_[1];
    float kqdj0 = (float)KQ_DO_[0], kqdj1 = (float)KQ_DO_[1];
    float bctt = TF(B_CT_, ta);
    float bijct0 = sqrtf(bctt * (float)B_CT_[0]), bijct1 = sqrtf(bctt * (float)B_CT_[1]);
    float inve0 = (ta == 0) ? 1e-15f : (float)(1.0 / EPS_OFF);
    float inve1 = (ta == 1) ? 1e-15f : (float)(1.0 / EPS_OFF);
    float spi = TF(SPA_, ta), kdpi = TF(KD_PA_, ta), kqpi = TF(KQ_PA_, ta);
    float spj0 = (float)SPA_[0], spj1 = (float)SPA_[1];
    float kdpj0 = (float)KD_PA_[0], kdpj1 = (float)KD_PA_[1];
    float kqpj0 = (float)KQ_PA_[0], kqpj1 = (float)KQ_PA_[1];
    float bpat = TF(B_PA_, ta);
    float bijpa0 = sqrtf(bpat * (float)B_PA_[0]), bijpa1 = sqrtf(bpat * (float)B_PA_[1]);
    float bxpt = TF(B_XP_, ta);
    float bijxp0 = sqrtf(bxpt * (float)B_XP_[0]), bijxp1 = sqrtf(bxpt * (float)B_XP_[1]);
    float sxpi = TF(SXP_, ta);
    float cxp0 = sxpi * (float)SXP_[0], cxp1 = sxpi * (float)SXP_[1];
    float bdt = TF(B_D_, ta);
    float bijd0 = sqrtf(bdt * (float)B_D_[0]), bijd1 = sqrtf(bdt * (float)B_D_[1]);
    float c6t = TF(C6_, ta);
    float c60 = sqrtf(c6t * (float)C6_[0]), c61 = sqrtf(c6t * (float)C6_[1]);

    // ---- phase 2: dense pair loop, block-strided over all survivors ----
    float e = 0.f, efx = 0.f, efy = 0.f, efz = 0.f, dqa = 0.f;
    for (int g = tid; g < total; g += 256) {
        MAP_SLOT(g, slot);
        float4 E4 = sh_list[slot];
        f3 dr = {E4.x, E4.y, E4.z};
        int b = __float_as_int(E4.w);
        int wb = b / 3;
        int tb = (b - wb * 3) ? 1 : 0;
        float r2 = dotf(dr, dr);
        float invr = rsqrtf(r2);
        float r = r2 * invr;
        f3 nv = dr * invr;
        float invr2 = invr * invr, invr3 = invr2 * invr;

        const float* MB = &sh_muQ[slot * 9];
        f3 mub = {MB[0], MB[1], MB[2]};
        float muin = dotf(mua, nv), mujn = dotf(mub, nv);
        float nQni = Qaxx * nv.x * nv.x + Qayy * nv.y * nv.y + Qazz * nv.z * nv.z +
                     2.f * (Qaxy * nv.x * nv.y + Qaxz * nv.x * nv.z + Qayz * nv.y * nv.z);
        float nQnj = MB[3] * nv.x * nv.x + MB[6] * nv.y * nv.y + MB[8] * nv.z * nv.z +
                     2.f * (MB[4] * nv.x * nv.y + MB[5] * nv.x * nv.z + MB[7] * nv.y * nv.z);

        // permanent electrostatics (e_qq rearranged: no large-term cancellation)
        float fdm = f1mf(S(bije) * r);
        float fd = 1.f + fdm;
        float ep = (S(qq) + S(Ziqj) * f1mf(S(belj) * r) + S(Zjqi) * f1mf(beli * r) +
                    S(qiqj) * fdm) * invr;
        ep += fd * (S(qtj) * muin - qti * mujn) * invr2;
        ep += fd * (dotf(mua, mub) - 3.f * muin * mujn) * invr3;
        ep += 3.f * fd * (qti * nQnj + S(qtj) * nQni) * invr3;

        // field at atom a
        float cc = -S(qtj) * invr2 + 3.f * mujn * invr3;
        efx += fd * (cc * nv.x - mub.x * invr3);
        efy += fd * (cc * nv.y - mub.y * invr3);
        efz += fd * (cc * nv.z - mub.z * invr3);

        // charge transfer
        float sdon_i = sdi + kddi * muin + kqdi * nQni;
        float sdon_j = S(sdj) - S(kddj) * mujn + S(kqdj) * nQnj;
        float sct_r = __expf(-S(bijct) * r) * invr;
        ep -= (sdon_i * S(saccj) + sdon_j * sacci) * sct_r;
        dqa += sdon_j * sacci * sct_r * S(inve);

        // Pauli repulsion
        float si = spi + kdpi * muin + kqpi * nQni;
        float sj = S(spj) - S(kdpj) * mujn + S(kqpj) * nQnj;
        ep += si * sj * __expf(-S(bijpa) * r) * invr;

        // exchange polarization
        ep -= S(cxp) * __expf(-S(bijxp) * r) * invr;

        // Tang-Toennies dispersion
        float u = S(bijd) * r;
        float poly = 1.f + u * (1.f + u * (0.5f + u * (0.16666667f + u * (4.1666667e-2f +
                     u * (8.3333333e-3f + u * 1.3888889e-3f)))));
        ep -= (1.f - __expf(-u) * poly) * S(c6) * invr3 * invr3;

        e += ep;
    }

    // ---- reduction: wave shuffle (f32), then cross-wave via LDS (f64) ----
    e = wredf(e); efx = wredf(efx); efy = wredf(efy); efz = wredf(efz); dqa = wredf(dqa);
    if (lane == 0) {
        sh_red[w * 5 + 0] = (double)e;
        sh_red[w * 5 + 1] = (double)efx;
        sh_red[w * 5 + 2] = (double)efy;
        sh_red[w * 5 + 3] = (double)efz;
        sh_red[w * 5 + 4] = (double)dqa;
    }
    __syncthreads();

    if (tid == 0) {
        double se = 0, sx = 0, sy = 0, sz = 0, sq = 0;
        for (int k = 0; k < NWAVE; ++k) {
            se += sh_red[k * 5 + 0];
            sx += sh_red[k * 5 + 1];
            sy += sh_red[k * 5 + 2];
            sz += sh_red[k * 5 + 3];
            sq += sh_red[k * 5 + 4];
        }
        double tot = 0.5 * se;

        // ---- f32 tail (short chains; error budget ~1e-5 rel per atom) ----
        float sxf = (float)sx, syf = (float)sy, szf = (float)sz;
        // polarization: -1/2 E.alpha.E, alpha = Ra diag Ra^T  -> v = Ra^T E
        float v0 = Ra[0][0] * sxf + Ra[1][0] * syf + Ra[2][0] * szf;
        float v1 = Ra[0][1] * sxf + Ra[1][1] * syf + Ra[2][1] * szf;
        float v2 = Ra[0][2] * sxf + Ra[1][2] * syf + Ra[2][2] * szf;
        float ad0 = ta ? (float)AD_[1][0] : (float)AD_[0][0];
        float ad1 = ta ? (float)AD_[1][1] : (float)AD_[0][1];
        float ad2 = ta ? (float)AD_[1][2] : (float)AD_[0][2];
        float pol = -0.5f * (ad0 * v0 * v0 + ad1 * v1 * v1 + ad2 * v2 * v2);
        // indirect charge transfer
        float dqf = (float)sq;
        float eta = ta ? (float)ETA_[1] : (float)ETA_[0];
        float ctind = 0.5f * eta * dqf * dqf;
        tot += (double)pol + (double)ctind;

        // bonded terms: O-blocks handle their water (f32 chains)
        if (ta == 0) {
            f3 cO = getcf(coords, 3 * wa);
            f3 b1 = pbcf(getcf(coords, 3 * wa + 1) - cO, B);
            f3 b2 = pbcf(getcf(coords, 3 * wa + 2) - cO, B);
            float l1 = sqrtf(dotf(b1, b1)), l2 = sqrtf(dotf(b2, b2));
            float bf = sqrtf((float)(K_B / (2.0 * D_M)));
            float d1 = l1 - (float)B_EQ, d2 = l2 - (float)B_EQ;
            float x1 = 1.f - __expf(-bf * d1);
            float x2 = 1.f - __expf(-bf * d2);
            float eb = (float)D_M * (x1 * x1 + x2 * x2);
            eb += (float)K_BB * d1 * d2;
            float cang = dotf(b1, b2) / (l1 * l2);
            cang = fminf(fmaxf(cang, -1.f + 1e-7f), 1.f - 1e-7f);
            float th = acosf(cang);
            float cte = cosf((float)TH_EQ);
            float dc = cang - cte;
            eb += 0.5f * (float)K_TH * dc * dc;
            eb += (float)K_BA * (d1 + d2) * (th - (float)TH_EQ);
            tot += (double)eb;
        }
        wsd[a] = tot;   // deterministic per-atom partial
    }
}

// =============== kernel 2: deterministic final reduce ===============
__global__ void __launch_bounds__(256) k_final(const double* __restrict__ wsd,
                                               float* __restrict__ out, int N) {
    int tid = threadIdx.x;
    int w = tid >> 6, lane = tid & 63;
    double v = 0.0;
    for (int i = tid; i < N; i += 256) v += wsd[i];
    v = wredd(v);
    __shared__ double s[4];
    if (lane == 0) s[w] = v;
    __syncthreads();
    if (tid == 0) out[0] = (float)(s[0] + s[1] + s[2] + s[3]);
}

extern "C" void kernel_launch(void* const* d_in, const int* in_sizes, int n_in,
                              void* d_out, int out_size, void* d_ws, size_t ws_size,
                              hipStream_t stream) {
    const float* coords = (const float*)d_in[0];
    const float* box    = (const float*)d_in[1];
    int N = in_sizes[0] / 3;  // atoms (768)
    double* wsd = (double*)d_ws;
    float* out = (float*)d_out;

    k_main<<<N, 256, 0, stream>>>(coords, box, wsd, N);
    k_final<<<1, 256, 0, stream>>>(wsd, out, N);
}